// Round 6
// baseline (60.766 us; speedup 1.0000x reference)
//
#include <hip/hip_runtime.h>
#include <hip/hip_bf16.h>

#define Bn 8
#define Cn 128
#define Hn 64
#define Wn 64
#define HWn 4096
#define KK 9

typedef short short8 __attribute__((ext_vector_type(8)));
typedef float f32x4 __attribute__((ext_vector_type(4)));

__device__ inline unsigned short f2b(float v) {
    __hip_bfloat16 h = __float2bfloat16(v);
    return *reinterpret_cast<unsigned short*>(&h);
}

// ---------------------------------------------------------------------------
// K1: per-(b,c) plane streaming sums (stride 10):
//  [0]=sum(X2) [1]=row0 [2]=row63 [3]=col0 [4]=col63 [5]=sum(Y2)
//  [6]=x00 [7]=x063 [8]=x630 [9]=x6363
// ---------------------------------------------------------------------------
__global__ __launch_bounds__(256) void k_pre(
    const float* __restrict__ X2, const float* __restrict__ Y2,
    float* __restrict__ pws)
{
    int bc = blockIdx.x, t = threadIdx.x;
    const float4* xp = (const float4*)(X2 + (size_t)bc * HWn);
    const float4* yp = (const float4*)(Y2 + (size_t)bc * HWn);
    float v[10];
#pragma unroll
    for (int k = 0; k < 10; k++) v[k] = 0.f;
#pragma unroll
    for (int i = 0; i < 4; i++) {
        int q = t + i * 256;
        float4 x = xp[q], y = yp[q];
        float s4 = x.x + x.y + x.z + x.w;
        v[0] += s4;
        v[5] += y.x + y.y + y.z + y.w;
        int px = q * 4, h = px >> 6, w4 = px & 63;
        if (h == 0)   v[1] += s4;
        if (h == 63)  v[2] += s4;
        if (w4 == 0)  v[3] += x.x;
        if (w4 == 60) v[4] += x.w;
        if (px == 0)    v[6] += x.x;
        if (px == 60)   v[7] += x.w;
        if (px == 4032) v[8] += x.x;
        if (px == 4092) v[9] += x.w;
    }
#pragma unroll
    for (int k = 0; k < 10; k++)
#pragma unroll
        for (int off = 32; off; off >>= 1)
            v[k] += __shfl_down(v[k], off);
    __shared__ float red[4][10];
    int lane = t & 63, wv = t >> 6;
    if (lane == 0) {
#pragma unroll
        for (int k = 0; k < 10; k++) red[wv][k] = v[k];
    }
    __syncthreads();
    if (t < 10) pws[bc * 10 + t] = red[0][t] + red[1][t] + red[2][t] + red[3][t];
}

// ---------------------------------------------------------------------------
// K2: 32 blocks (4 per batch). Closed-form mean(Xs), mean(Y2) -> MLP -> cf
// quarter. Also converts wf/ws slices to bf16.
// ---------------------------------------------------------------------------
__global__ __launch_bounds__(256) void k_ctx(
    const float* __restrict__ pws, const float* __restrict__ sw,
    const float* __restrict__ w1, const float* __restrict__ w2,
    const float* __restrict__ w3, const float* __restrict__ wf,
    const float* __restrict__ wsp, float* __restrict__ cf,
    unsigned short* __restrict__ wfb, unsigned short* __restrict__ wsb)
{
    int blk = blockIdx.x, b = blk >> 2, qd = blk & 3;
    int t = threadIdx.x;
    // weight conversion slices
    for (int i = t; i < 1024; i += 256) {
        int j = blk * 1024 + i;
        wfb[j] = f2b(wf[j]);
    }
    {
        int j = blk * 128 + t;     // t<128 covers; guard others
        if (t < 128) {
            int tt = j >> 8, c = j & 255;
            wsb[j] = (tt < KK) ? f2b(wsp[tt * 256 + c]) : (unsigned short)0;
        }
    }
    __shared__ float mfc[256], c1[64], c2[64];
    if (t < 128) {
        const float* S = pws + (b * Cn + t) * 10;
        float T = S[0];
        float R[3]  = { S[2], 0.f, S[1] };
        float Cc[3] = { S[4], 0.f, S[3] };
        float Xc[3][3] = {{S[9], 0.f, S[8]}, {0.f, 0.f, 0.f}, {S[7], 0.f, S[6]}};
        float a = 0.f;
#pragma unroll
        for (int i = 0; i < 3; i++)
#pragma unroll
            for (int j = 0; j < 3; j++)
                a += sw[t * 9 + i * 3 + j] * (T - R[i] - Cc[j] + Xc[i][j]);
        mfc[t] = a * (1.f / HWn);
    } else {
        mfc[t] = pws[(b * Cn + (t - 128)) * 10 + 5] * (1.f / HWn);
    }
    __syncthreads();
    if (t < 64) {
        const float4* wr = (const float4*)(w1 + t * 256);
        float a = 0.f;
        for (int c = 0; c < 64; c++) {
            float4 v = wr[c];
            a += v.x * mfc[c*4] + v.y * mfc[c*4+1] + v.z * mfc[c*4+2] + v.w * mfc[c*4+3];
        }
        c1[t] = a;
    }
    __syncthreads();
    if (t < 64) {
        const float4* wr = (const float4*)(w2 + t * 64);
        float a = 0.f;
        for (int c = 0; c < 16; c++) {
            float4 v = wr[c];
            a += v.x * c1[c*4] + v.y * c1[c*4+1] + v.z * c1[c*4+2] + v.w * c1[c*4+3];
        }
        c2[t] = fmaxf(a, 0.f);
    }
    __syncthreads();
    for (int j = qd * 288 + t; j < qd * 288 + 288; j += 256) {
        const float4* wr = (const float4*)(w3 + j * 64);
        float a = 0.f;
        for (int c = 0; c < 16; c++) {
            float4 v = wr[c];
            a += v.x * c2[c*4] + v.y * c2[c*4+1] + v.z * c2[c*4+2] + v.w * c2[c*4+3];
        }
        cf[b * Cn * KK + j] = a;
    }
}

// ---------------------------------------------------------------------------
// K3: one block per (b,h): 512 threads, full w=64 row. Taps in registers,
// shfl for w+-1, both convs from regs. Swizzled bf16 LDS, b128 packed writes.
// ---------------------------------------------------------------------------
__global__ __launch_bounds__(512, 4) void k_main(
    const float* __restrict__ X2, const float* __restrict__ Y2,
    const float* __restrict__ sw,
    const unsigned short* __restrict__ wfb, const unsigned short* __restrict__ wsb,
    const float* __restrict__ cf, float* __restrict__ out)
{
    __shared__ unsigned short sFt[2][Wn][Cn];  // 32 KB, col swizzled c^((w&7)<<3)
    __shared__ float sSf[KK][Wn];              // 2.25 KB
    __shared__ float sCfP[Cn][12];             // 6 KB (padded rows, 16B-aligned)
    __shared__ float sSwP[Cn][12];             // 6 KB

    int bid = blockIdx.x;
    int b = bid & 7, h = bid >> 3;             // XCD-chunked: batch per XCD
    int t = threadIdx.x;
    int w = t & 63, cg = t >> 6;               // cg in [0,8), 16 channels each
    int swz = (w & 7) << 3;
    int c0 = cg * 16;

    for (int i = t; i < Cn * KK; i += 512) {
        int c = i / 9, q = i - c * 9;
        sSwP[c][q] = sw[i];
        sCfP[c][q] = cf[b * Cn * KK + i];
    }
    __syncthreads();

    const float* xcol = X2 + (size_t)(b * Cn + c0) * HWn + h * Wn + w;
    const float* ycol = Y2 + (size_t)(b * Cn + c0) * HWn + h * Wn + w;
    bool hm = h > 0, hp = h < Hn - 1;
    bool wm = w > 0, wp = w < Wn - 1;

    float tap[16][3];

    // ---- Phase 0: load taps, static conv + Y2 -> LDS (b128-packed)
    {
        unsigned int px[4], py[4];
#pragma unroll
        for (int i = 0; i < 16; i++) {
            int c = c0 + i;
            const float* xp = xcol + (size_t)i * HWn;
            float r0 = hm ? xp[-Wn] : 0.f;
            float r1 = xp[0];
            float r2 = hp ? xp[Wn] : 0.f;
            tap[i][0] = r0; tap[i][1] = r1; tap[i][2] = r2;
            float4 k0 = *(const float4*)&sSwP[c][0];
            float4 k1 = *(const float4*)&sSwP[c][4];
            float  k8 = sSwP[c][8];
            float xl0 = __shfl_up(r0, 1), xr0 = __shfl_down(r0, 1);
            float xl1 = __shfl_up(r1, 1), xr1 = __shfl_down(r1, 1);
            float xl2 = __shfl_up(r2, 1), xr2 = __shfl_down(r2, 1);
            if (!wm) { xl0 = 0.f; xl1 = 0.f; xl2 = 0.f; }
            if (!wp) { xr0 = 0.f; xr1 = 0.f; xr2 = 0.f; }
            float a = k0.x * xl0 + k0.y * r0 + k0.z * xr0
                    + k0.w * xl1 + k1.x * r1 + k1.y * xr1
                    + k1.z * xl2 + k1.w * r2 + k8 * xr2;
            float yv = ycol[(size_t)i * HWn];
            unsigned int ah = f2b(a), yh = f2b(yv);
            int sub = i & 7;
            if ((sub & 1) == 0) { px[sub >> 1] = ah; py[sub >> 1] = yh; }
            else { px[sub >> 1] |= ah << 16; py[sub >> 1] |= yh << 16; }
            if (sub == 7) {
                int col = (c - 7) ^ swz;
                *(uint4*)(&sFt[0][w][col]) = *(uint4*)px;
                *(uint4*)(&sFt[1][w][col]) = *(uint4*)py;
            }
        }
    }
    __syncthreads();

    // ---- Phase A: sf[16][64] = wsb[16][256] @ [Xs;Y2] (rows 9..15 zero)
    {
        int lane = t & 63, wv = t >> 6;
        int l16 = lane & 15, half = lane >> 4, kk = half * 8;
        if (wv < 4) {
            int wA = wv * 16 + l16;
            int swzA = (wA & 7) << 3;
            f32x4 acc = (f32x4){0.f, 0.f, 0.f, 0.f};
#pragma unroll
            for (int ks = 0; ks < 8; ks++) {
                short8 av = *(const short8*)(wsb + l16 * 256 + ks * 32 + kk);
                int col = (((ks & 3) * 32 + kk)) ^ swzA;
                short8 bv = *(const short8*)(&sFt[ks >> 2][wA][0] + col);
                acc = __builtin_amdgcn_mfma_f32_16x16x32_bf16(av, bv, acc, 0, 0, 0);
            }
#pragma unroll
            for (int r = 0; r < 4; r++) {
                int tt = half * 4 + r;
                if (tt < KK) sSf[tt][wA] = acc[r];
            }
        }
    }
    __syncthreads();

    // ---- Phase B: dyn from register taps + shfl
    {
        float sfw[9];
#pragma unroll
        for (int q = 0; q < 9; q++) sfw[q] = sSf[q][w];
        unsigned int pd[4];
#pragma unroll
        for (int i = 0; i < 16; i++) {
            int c = c0 + i;
            float r0 = tap[i][0], r1 = tap[i][1], r2 = tap[i][2];
            float4 e0 = *(const float4*)&sCfP[c][0];
            float4 e1 = *(const float4*)&sCfP[c][4];
            float  e8 = sCfP[c][8];
            float xl0 = __shfl_up(r0, 1), xr0 = __shfl_down(r0, 1);
            float xl1 = __shfl_up(r1, 1), xr1 = __shfl_down(r1, 1);
            float xl2 = __shfl_up(r2, 1), xr2 = __shfl_down(r2, 1);
            if (!wm) { xl0 = 0.f; xl1 = 0.f; xl2 = 0.f; }
            if (!wp) { xr0 = 0.f; xr1 = 0.f; xr2 = 0.f; }
            float a = (e0.x + sfw[0]) * xl0 + (e0.y + sfw[1]) * r0 + (e0.z + sfw[2]) * xr0
                    + (e0.w + sfw[3]) * xl1 + (e1.x + sfw[4]) * r1 + (e1.y + sfw[5]) * xr1
                    + (e1.z + sfw[6]) * xl2 + (e1.w + sfw[7]) * r2 + (e8 + sfw[8]) * xr2;
            unsigned int ah = f2b(a);
            int sub = i & 7;
            if ((sub & 1) == 0) pd[sub >> 1] = ah;
            else pd[sub >> 1] |= ah << 16;
            if (sub == 7) {
                int col = (c - 7) ^ swz;
                *(uint4*)(&sFt[1][w][col]) = *(uint4*)pd;
            }
        }
    }
    __syncthreads();

    // ---- Phase C: out[o][w] = sum_k wf[o][k] * [Xs;dyn][k][w], K=256.
    // 8 waves, wave wv owns o in [wv*16, wv*16+16).
    {
        int lane = t & 63, wv = t >> 6;
        int l16 = lane & 15, half = lane >> 4, kk = half * 8;
        int o0 = wv * 16;
        f32x4 acc[4];
#pragma unroll
        for (int n = 0; n < 4; n++) acc[n] = (f32x4){0.f, 0.f, 0.f, 0.f};
#pragma unroll
        for (int ks = 0; ks < 8; ks++) {
            int bufi = ks >> 2;
            int kc = (ks & 3) * 32 + kk;
            short8 av = *(const short8*)(wfb + (o0 + l16) * 256 + ks * 32 + kk);
#pragma unroll
            for (int n = 0; n < 4; n++) {
                int wB = n * 16 + l16;
                int col = kc ^ ((wB & 7) << 3);
                short8 bv = *(const short8*)(&sFt[bufi][wB][0] + col);
                acc[n] = __builtin_amdgcn_mfma_f32_16x16x32_bf16(av, bv, acc[n], 0, 0, 0);
            }
        }
        size_t obase = (size_t)b * Cn * HWn + (size_t)h * Wn;
#pragma unroll
        for (int n = 0; n < 4; n++)
#pragma unroll
            for (int r = 0; r < 4; r++) {
                int o = o0 + half * 4 + r;
                out[obase + (size_t)o * HWn + n * 16 + l16] = acc[n][r];
            }
    }
}

// ---------------------------------------------------------------------------
extern "C" void kernel_launch(void* const* d_in, const int* in_sizes, int n_in,
                              void* d_out, int out_size, void* d_ws, size_t ws_size,
                              hipStream_t stream) {
    (void)in_sizes; (void)n_in; (void)out_size; (void)ws_size;
    const float* X2  = (const float*)d_in[0];
    const float* Y2  = (const float*)d_in[1];
    const float* sw  = (const float*)d_in[2];
    const float* w1  = (const float*)d_in[3];
    const float* w2  = (const float*)d_in[4];
    const float* w3  = (const float*)d_in[5];
    const float* wsp = (const float*)d_in[6];
    const float* wf  = (const float*)d_in[7];
    float* out = (float*)d_out;

    float* wsf = (float*)d_ws;
    float* pws = wsf;                                      // 10240 f
    float* cf  = wsf + 10240;                              // 9216 f
    unsigned short* wfb = (unsigned short*)(wsf + 19456);  // 32768 u16
    unsigned short* wsb = (unsigned short*)(wsf + 35840);  // 4096 u16

    hipLaunchKernelGGL(k_pre, dim3(Bn * Cn), dim3(256), 0, stream, X2, Y2, pws);
    hipLaunchKernelGGL(k_ctx, dim3(32), dim3(256), 0, stream,
                       pws, sw, w1, w2, w3, wf, wsp, cf, wfb, wsb);
    hipLaunchKernelGGL(k_main, dim3(Bn * Hn), dim3(512), 0, stream,
                       X2, Y2, sw, wfb, wsb, cf, out);
}

// Round 7
// 49.689 us; speedup vs baseline: 1.2229x; 1.2229x over previous
//
#include <hip/hip_runtime.h>
#include <hip/hip_bf16.h>

#define Bn 8
#define Cn 128
#define Hn 64
#define Wn 64
#define HWn 4096
#define KK 9

typedef short short8 __attribute__((ext_vector_type(8)));
typedef float f32x4 __attribute__((ext_vector_type(4)));

__device__ inline unsigned short f2b(float v) {
    __hip_bfloat16 h = __float2bfloat16(v);
    return *reinterpret_cast<unsigned short*>(&h);
}

// ---------------------------------------------------------------------------
// K1: per-(b,c) plane streaming sums (stride 10):
//  [0]=sum(X2) [1]=row0 [2]=row63 [3]=col0 [4]=col63 [5]=sum(Y2)
//  [6]=x00 [7]=x063 [8]=x630 [9]=x6363
// ---------------------------------------------------------------------------
__global__ __launch_bounds__(256) void k_pre(
    const float* __restrict__ X2, const float* __restrict__ Y2,
    float* __restrict__ pws)
{
    int bc = blockIdx.x, t = threadIdx.x;
    const float4* xp = (const float4*)(X2 + (size_t)bc * HWn);
    const float4* yp = (const float4*)(Y2 + (size_t)bc * HWn);
    float v[10];
#pragma unroll
    for (int k = 0; k < 10; k++) v[k] = 0.f;
#pragma unroll
    for (int i = 0; i < 4; i++) {
        int q = t + i * 256;
        float4 x = xp[q], y = yp[q];
        float s4 = x.x + x.y + x.z + x.w;
        v[0] += s4;
        v[5] += y.x + y.y + y.z + y.w;
        int px = q * 4, h = px >> 6, w4 = px & 63;
        if (h == 0)   v[1] += s4;
        if (h == 63)  v[2] += s4;
        if (w4 == 0)  v[3] += x.x;
        if (w4 == 60) v[4] += x.w;
        if (px == 0)    v[6] += x.x;
        if (px == 60)   v[7] += x.w;
        if (px == 4032) v[8] += x.x;
        if (px == 4092) v[9] += x.w;
    }
#pragma unroll
    for (int k = 0; k < 10; k++)
#pragma unroll
        for (int off = 32; off; off >>= 1)
            v[k] += __shfl_down(v[k], off);
    __shared__ float red[4][10];
    int lane = t & 63, wv = t >> 6;
    if (lane == 0) {
#pragma unroll
        for (int k = 0; k < 10; k++) red[wv][k] = v[k];
    }
    __syncthreads();
    if (t < 10) pws[bc * 10 + t] = red[0][t] + red[1][t] + red[2][t] + red[3][t];
}

// ---------------------------------------------------------------------------
// K2: 32 blocks (4 per batch). Closed-form mean(Xs), mean(Y2) -> MLP -> cf
// quarter. Also converts wf/ws slices to bf16.
// ---------------------------------------------------------------------------
__global__ __launch_bounds__(256) void k_ctx(
    const float* __restrict__ pws, const float* __restrict__ sw,
    const float* __restrict__ w1, const float* __restrict__ w2,
    const float* __restrict__ w3, const float* __restrict__ wf,
    const float* __restrict__ wsp, float* __restrict__ cf,
    unsigned short* __restrict__ wfb, unsigned short* __restrict__ wsb)
{
    int blk = blockIdx.x, b = blk >> 2, qd = blk & 3;
    int t = threadIdx.x;
    // weight conversion slices
    for (int i = t; i < 1024; i += 256) {
        int j = blk * 1024 + i;
        wfb[j] = f2b(wf[j]);
    }
    {
        int j = blk * 128 + t;
        if (t < 128) {
            int tt = j >> 8, c = j & 255;
            wsb[j] = (tt < KK) ? f2b(wsp[tt * 256 + c]) : (unsigned short)0;
        }
    }
    __shared__ float mfc[256], c1[64], c2[64];
    if (t < 128) {
        const float* S = pws + (b * Cn + t) * 10;
        float T = S[0];
        float R[3]  = { S[2], 0.f, S[1] };
        float Cc[3] = { S[4], 0.f, S[3] };
        float Xc[3][3] = {{S[9], 0.f, S[8]}, {0.f, 0.f, 0.f}, {S[7], 0.f, S[6]}};
        float a = 0.f;
#pragma unroll
        for (int i = 0; i < 3; i++)
#pragma unroll
            for (int j = 0; j < 3; j++)
                a += sw[t * 9 + i * 3 + j] * (T - R[i] - Cc[j] + Xc[i][j]);
        mfc[t] = a * (1.f / HWn);
    } else {
        mfc[t] = pws[(b * Cn + (t - 128)) * 10 + 5] * (1.f / HWn);
    }
    __syncthreads();
    if (t < 64) {
        const float4* wr = (const float4*)(w1 + t * 256);
        float a = 0.f;
        for (int c = 0; c < 64; c++) {
            float4 v = wr[c];
            a += v.x * mfc[c*4] + v.y * mfc[c*4+1] + v.z * mfc[c*4+2] + v.w * mfc[c*4+3];
        }
        c1[t] = a;
    }
    __syncthreads();
    if (t < 64) {
        const float4* wr = (const float4*)(w2 + t * 64);
        float a = 0.f;
        for (int c = 0; c < 16; c++) {
            float4 v = wr[c];
            a += v.x * c1[c*4] + v.y * c1[c*4+1] + v.z * c1[c*4+2] + v.w * c1[c*4+3];
        }
        c2[t] = fmaxf(a, 0.f);
    }
    __syncthreads();
    for (int j = qd * 288 + t; j < qd * 288 + 288; j += 256) {
        const float4* wr = (const float4*)(w3 + j * 64);
        float a = 0.f;
        for (int c = 0; c < 16; c++) {
            float4 v = wr[c];
            a += v.x * c2[c*4] + v.y * c2[c*4+1] + v.z * c2[c*4+2] + v.w * c2[c*4+3];
        }
        cf[b * Cn * KK + j] = a;
    }
}

// ---------------------------------------------------------------------------
// K3: one block per (b,h): 512 threads, full w=64 row. Taps in registers
// (launch_bounds(512,2) -> VGPR cap 256, no spill), shfl for w+-1.
// Y2 loads + out stores nontemporal to keep X2 L2-resident.
// ---------------------------------------------------------------------------
__global__ __launch_bounds__(512, 2) void k_main(
    const float* __restrict__ X2, const float* __restrict__ Y2,
    const float* __restrict__ sw,
    const unsigned short* __restrict__ wfb, const unsigned short* __restrict__ wsb,
    const float* __restrict__ cf, float* __restrict__ out)
{
    __shared__ unsigned short sFt[2][Wn][Cn];  // 32 KB, col swizzled c^((w&7)<<3)
    __shared__ float sSf[KK][Wn];              // 2.25 KB
    __shared__ float sCfP[Cn][12];             // 6 KB
    __shared__ float sSwP[Cn][12];             // 6 KB

    int bid = blockIdx.x;
    int b = bid & 7, h = bid >> 3;             // XCD-chunked: batch per XCD
    int t = threadIdx.x;
    int w = t & 63, cg = t >> 6;               // cg in [0,8), 16 channels each
    int swz = (w & 7) << 3;
    int c0 = cg * 16;

    for (int i = t; i < Cn * KK; i += 512) {
        int c = i / 9, q = i - c * 9;
        sSwP[c][q] = sw[i];
        sCfP[c][q] = cf[b * Cn * KK + i];
    }

    const float* xcol = X2 + (size_t)(b * Cn + c0) * HWn + h * Wn + w;
    const float* ycol = Y2 + (size_t)(b * Cn + c0) * HWn + h * Wn + w;
    bool hm = h > 0, hp = h < Hn - 1;
    bool wm = w > 0, wp = w < Wn - 1;

    float tap[16][3];
    float yv[16];

    // ---- Load ALL taps + Y2 first (64 independent loads in flight)
#pragma unroll
    for (int i = 0; i < 16; i++) {
        const float* xp = xcol + (size_t)i * HWn;
        tap[i][0] = hm ? xp[-Wn] : 0.f;
        tap[i][1] = xp[0];
        tap[i][2] = hp ? xp[Wn] : 0.f;
        yv[i] = __builtin_nontemporal_load(ycol + (size_t)i * HWn);
    }
    __syncthreads();   // sSwP/sCfP ready

    // ---- Phase 0: static conv from register taps -> LDS (b128-packed)
    {
        unsigned int px[4], py[4];
#pragma unroll
        for (int i = 0; i < 16; i++) {
            int c = c0 + i;
            float r0 = tap[i][0], r1 = tap[i][1], r2 = tap[i][2];
            float4 k0 = *(const float4*)&sSwP[c][0];
            float4 k1 = *(const float4*)&sSwP[c][4];
            float  k8 = sSwP[c][8];
            float xl0 = __shfl_up(r0, 1), xr0 = __shfl_down(r0, 1);
            float xl1 = __shfl_up(r1, 1), xr1 = __shfl_down(r1, 1);
            float xl2 = __shfl_up(r2, 1), xr2 = __shfl_down(r2, 1);
            if (!wm) { xl0 = 0.f; xl1 = 0.f; xl2 = 0.f; }
            if (!wp) { xr0 = 0.f; xr1 = 0.f; xr2 = 0.f; }
            float a = k0.x * xl0 + k0.y * r0 + k0.z * xr0
                    + k0.w * xl1 + k1.x * r1 + k1.y * xr1
                    + k1.z * xl2 + k1.w * r2 + k8 * xr2;
            unsigned int ah = f2b(a), yh = f2b(yv[i]);
            int sub = i & 7;
            if ((sub & 1) == 0) { px[sub >> 1] = ah; py[sub >> 1] = yh; }
            else { px[sub >> 1] |= ah << 16; py[sub >> 1] |= yh << 16; }
            if (sub == 7) {
                int col = (c - 7) ^ swz;
                *(uint4*)(&sFt[0][w][col]) = *(uint4*)px;
                *(uint4*)(&sFt[1][w][col]) = *(uint4*)py;
            }
        }
    }
    __syncthreads();

    // ---- Phase A: sf[16][64] = wsb[16][256] @ [Xs;Y2] (rows 9..15 zero)
    {
        int lane = t & 63, wv = t >> 6;
        int l16 = lane & 15, half = lane >> 4, kk = half * 8;
        if (wv < 4) {
            int wA = wv * 16 + l16;
            int swzA = (wA & 7) << 3;
            f32x4 acc = (f32x4){0.f, 0.f, 0.f, 0.f};
#pragma unroll
            for (int ks = 0; ks < 8; ks++) {
                short8 av = *(const short8*)(wsb + l16 * 256 + ks * 32 + kk);
                int col = (((ks & 3) * 32 + kk)) ^ swzA;
                short8 bv = *(const short8*)(&sFt[ks >> 2][wA][0] + col);
                acc = __builtin_amdgcn_mfma_f32_16x16x32_bf16(av, bv, acc, 0, 0, 0);
            }
#pragma unroll
            for (int r = 0; r < 4; r++) {
                int tt = half * 4 + r;
                if (tt < KK) sSf[tt][wA] = acc[r];
            }
        }
    }
    __syncthreads();

    // ---- Phase B: dyn from register taps + shfl
    {
        float sfw[9];
#pragma unroll
        for (int q = 0; q < 9; q++) sfw[q] = sSf[q][w];
        unsigned int pd[4];
#pragma unroll
        for (int i = 0; i < 16; i++) {
            int c = c0 + i;
            float r0 = tap[i][0], r1 = tap[i][1], r2 = tap[i][2];
            float4 e0 = *(const float4*)&sCfP[c][0];
            float4 e1 = *(const float4*)&sCfP[c][4];
            float  e8 = sCfP[c][8];
            float xl0 = __shfl_up(r0, 1), xr0 = __shfl_down(r0, 1);
            float xl1 = __shfl_up(r1, 1), xr1 = __shfl_down(r1, 1);
            float xl2 = __shfl_up(r2, 1), xr2 = __shfl_down(r2, 1);
            if (!wm) { xl0 = 0.f; xl1 = 0.f; xl2 = 0.f; }
            if (!wp) { xr0 = 0.f; xr1 = 0.f; xr2 = 0.f; }
            float a = (e0.x + sfw[0]) * xl0 + (e0.y + sfw[1]) * r0 + (e0.z + sfw[2]) * xr0
                    + (e0.w + sfw[3]) * xl1 + (e1.x + sfw[4]) * r1 + (e1.y + sfw[5]) * xr1
                    + (e1.z + sfw[6]) * xl2 + (e1.w + sfw[7]) * r2 + (e8 + sfw[8]) * xr2;
            unsigned int ah = f2b(a);
            int sub = i & 7;
            if ((sub & 1) == 0) pd[sub >> 1] = ah;
            else pd[sub >> 1] |= ah << 16;
            if (sub == 7) {
                int col = (c - 7) ^ swz;
                *(uint4*)(&sFt[1][w][col]) = *(uint4*)pd;
            }
        }
    }
    __syncthreads();

    // ---- Phase C: out[o][w] = sum_k wf[o][k] * [Xs;dyn][k][w], K=256.
    {
        int lane = t & 63, wv = t >> 6;
        int l16 = lane & 15, half = lane >> 4, kk = half * 8;
        int o0 = wv * 16;
        f32x4 acc[4];
#pragma unroll
        for (int n = 0; n < 4; n++) acc[n] = (f32x4){0.f, 0.f, 0.f, 0.f};
#pragma unroll
        for (int ks = 0; ks < 8; ks++) {
            int bufi = ks >> 2;
            int kc = (ks & 3) * 32 + kk;
            short8 av = *(const short8*)(wfb + (o0 + l16) * 256 + ks * 32 + kk);
#pragma unroll
            for (int n = 0; n < 4; n++) {
                int wB = n * 16 + l16;
                int col = kc ^ ((wB & 7) << 3);
                short8 bv = *(const short8*)(&sFt[bufi][wB][0] + col);
                acc[n] = __builtin_amdgcn_mfma_f32_16x16x32_bf16(av, bv, acc[n], 0, 0, 0);
            }
        }
        size_t obase = (size_t)b * Cn * HWn + (size_t)h * Wn;
#pragma unroll
        for (int n = 0; n < 4; n++)
#pragma unroll
            for (int r = 0; r < 4; r++) {
                int o = o0 + half * 4 + r;
                __builtin_nontemporal_store(
                    acc[n][r], &out[obase + (size_t)o * HWn + n * 16 + l16]);
            }
    }
}

// ---------------------------------------------------------------------------
extern "C" void kernel_launch(void* const* d_in, const int* in_sizes, int n_in,
                              void* d_out, int out_size, void* d_ws, size_t ws_size,
                              hipStream_t stream) {
    (void)in_sizes; (void)n_in; (void)out_size; (void)ws_size;
    const float* X2  = (const float*)d_in[0];
    const float* Y2  = (const float*)d_in[1];
    const float* sw  = (const float*)d_in[2];
    const float* w1  = (const float*)d_in[3];
    const float* w2  = (const float*)d_in[4];
    const float* w3  = (const float*)d_in[5];
    const float* wsp = (const float*)d_in[6];
    const float* wf  = (const float*)d_in[7];
    float* out = (float*)d_out;

    float* wsf = (float*)d_ws;
    float* pws = wsf;                                      // 10240 f
    float* cf  = wsf + 10240;                              // 9216 f
    unsigned short* wfb = (unsigned short*)(wsf + 19456);  // 32768 u16
    unsigned short* wsb = (unsigned short*)(wsf + 35840);  // 4096 u16

    hipLaunchKernelGGL(k_pre, dim3(Bn * Cn), dim3(256), 0, stream, X2, Y2, pws);
    hipLaunchKernelGGL(k_ctx, dim3(32), dim3(256), 0, stream,
                       pws, sw, w1, w2, w3, wf, wsp, cf, wfb, wsb);
    hipLaunchKernelGGL(k_main, dim3(Bn * Hn), dim3(512), 0, stream,
                       X2, Y2, sw, wfb, wsb, cf, out);
}